// Round 2
// baseline (98.011 us; speedup 1.0000x reference)
//
#include <hip/hip_runtime.h>
#include <math.h>

#define B_ 8
#define BIGF 3.4e38f

// ws layout (16-B aligned base):
//   packT  : B_*N float4 {x,y,z,|t|^2}
//   packS  : B_*M float4 {x,y,z,|s|^2}
//   minarr : B_*N uint rowmin (per-target min d^2, uint-ordered floats)
//            followed by B_*M uint colmin (per-source min d^2)

// Pack points to float4 (plain form; -2 scaling applied at query load),
// init the min arrays to +inf, zero d_out. One node, ~1.5 us.
__global__ __launch_bounds__(256) void pack_kernel(
    const float* __restrict__ tar, const float* __restrict__ src,
    float4* __restrict__ packT, float4* __restrict__ packS,
    unsigned int* __restrict__ minarr, float* __restrict__ outp,
    int N, int M)
{
    const int i = blockIdx.x * 256 + threadIdx.x;
    const int nT = B_ * N, nS = B_ * M;
    if (i < nT) {
        float x = tar[3 * i], y = tar[3 * i + 1], z = tar[3 * i + 2];
        packT[i] = make_float4(x, y, z, fmaf(x, x, fmaf(y, y, z * z)));
    } else if (i < nT + nS) {
        int j = i - nT;
        float x = src[3 * j], y = src[3 * j + 1], z = src[3 * j + 2];
        packS[j] = make_float4(x, y, z, fmaf(x, x, fmaf(y, y, z * z)));
    }
    if (i < nT + nS) minarr[i] = 0x7F800000u;  // +inf
    if (i < 3) outp[i] = 0.f;                  // accuracy, complete, chamfer
}

// Two-pass structure (both dirs via z), packed-float4 I/O.
// blockIdx.z in [0, 2*B_): z<B_ query=tar ref=src; else query=src ref=tar.
// d^2 = |q|^2 + (|p|^2 - 2 q.p): inner = 3 fma/pair + min3/2pairs; |q|^2
// added after the min (monotone).
//
// R2 (this round): broadcast refs through the REGISTER FILE, not LDS.
// R3-LDS post-mortem: wave-uniform ds_read_b128 broadcasts saturated the
// per-CU shared LDS pipe (~86% busy: 16 waves x 8 b128 x 12cy = 1536 LDS-cy
// per 1792 VALU-cy round) and the bursty lgkmcnt waits on that queue
// serialized. R4-scalar post-mortem: re-reading refs from global/k$ per
// iteration put ~200cy cache latency on the critical path -> 93us.
// Fix: each wave holds the block's 128 refs in 8 VGPRs (two coalesced
// float4 loads; lane l owns refs l and 64+l), then v_readlane_b32 (uniform
// loop index -> SGPR) broadcasts each ref; the SGPR feeds v_fma_f32 directly
// as its single allowed SGPR operand. Inner loop: pure VALU, zero LDS, zero
// VMEM, no __syncthreads. 66 VALU / 16 pairs = 4.1 ops/pair (14us floor).
// Cross-block combine: distributed uint atomicMin (d^2 clamped >= 0 so uint
// order == float order).
template <int QPT, int CHUNK>
__global__ __launch_bounds__(256) void minsq_kernel(
    const float4* __restrict__ packT, const float4* __restrict__ packS,
    unsigned int* __restrict__ minarr, int N, int M)
{
    const int z   = blockIdx.z;
    const int dir = (z >= B_) ? 1 : 0;
    const int b   = dir ? (z - B_) : z;
    const float4* __restrict__ qry = dir ? packS : packT;
    const float4* __restrict__ pts = dir ? packT : packS;
    const int K = dir ? M : N;   // query count
    const int L = dir ? N : M;   // reference count
    unsigned int* __restrict__ out =
        minarr + (dir ? (size_t)B_ * N : (size_t)0) + (size_t)b * K;

    const int base = blockIdx.y * CHUNK;
    if (base >= L) return;
    const int cnt = min(CHUNK, L - base);
    const float4* __restrict__ psrc = pts + (size_t)b * L + base;

    const int t = threadIdx.x;
    const int lane = t & 63;
    const int qbase = blockIdx.x * (256 * QPT);
    float qx2[QPT], qy2[QPT], qz2[QPT], qw[QPT], mn[QPT];
#pragma unroll
    for (int k = 0; k < QPT; ++k) {
        int qi = qbase + k * 256 + t;
        if (qi < K) {
            float4 q = qry[(size_t)b * K + qi];
            qx2[k] = -2.f * q.x; qy2[k] = -2.f * q.y; qz2[k] = -2.f * q.z;
            qw[k] = q.w;
        } else {
            qx2[k] = 0.f; qy2[k] = 0.f; qz2[k] = 0.f; qw[k] = 0.f;
        }
        mn[k] = BIGF;
    }

    if (cnt == CHUNK) {
        // Wave-resident refs: lane l holds refs l and 64+l (8 VGPRs total).
        float4 r0 = psrc[lane];
        float4 r1 = psrc[64 + lane];
#pragma unroll 2
        for (int l = 0; l < 64; ++l) {
            // uniform lane index -> v_readlane_b32 into SGPRs (free broadcast)
            float p0x = __uint_as_float(__builtin_amdgcn_readlane(__float_as_uint(r0.x), l));
            float p0y = __uint_as_float(__builtin_amdgcn_readlane(__float_as_uint(r0.y), l));
            float p0z = __uint_as_float(__builtin_amdgcn_readlane(__float_as_uint(r0.z), l));
            float p0w = __uint_as_float(__builtin_amdgcn_readlane(__float_as_uint(r0.w), l));
            float p1x = __uint_as_float(__builtin_amdgcn_readlane(__float_as_uint(r1.x), l));
            float p1y = __uint_as_float(__builtin_amdgcn_readlane(__float_as_uint(r1.y), l));
            float p1z = __uint_as_float(__builtin_amdgcn_readlane(__float_as_uint(r1.z), l));
            float p1w = __uint_as_float(__builtin_amdgcn_readlane(__float_as_uint(r1.w), l));
#pragma unroll
            for (int k = 0; k < QPT; ++k) {
                float d0 = fmaf(qx2[k], p0x, fmaf(qy2[k], p0y,
                           fmaf(qz2[k], p0z, p0w)));
                float d1 = fmaf(qx2[k], p1x, fmaf(qy2[k], p1y,
                           fmaf(qz2[k], p1z, p1w)));
                mn[k] = fminf(mn[k], fminf(d0, d1));   // v_min3_f32
            }
        }
    } else {
        // generic tail (unused for N=M=4096; kept for correctness)
        for (int j = 0; j < cnt; ++j) {
            float4 p0 = psrc[j];
#pragma unroll
            for (int k = 0; k < QPT; ++k) {
                float d0 = fmaf(qx2[k], p0.x, fmaf(qy2[k], p0.y,
                           fmaf(qz2[k], p0.z, p0.w)));
                mn[k] = fminf(mn[k], d0);
            }
        }
    }

#pragma unroll
    for (int k = 0; k < QPT; ++k) {
        int qi = qbase + k * 256 + t;
        if (qi < K) {
            float d2 = fmaxf(mn[k] + qw[k], 0.f);  // clamp roundoff negatives
            atomicMin(&out[qi], __float_as_uint(d2));
        }
    }
}

// Merged reduce+finalize: 32 blocks stripe-sum sqrt of both regions, then 3
// scaled atomicAdds into d_out (zeroed by pack_kernel). 96 same-line atomics
// ~1.4 us — cheaper than a second reduce node (~2.6 us gap).
__global__ __launch_bounds__(256) void reduce_kernel(
    const unsigned int* __restrict__ minarr, float* __restrict__ outp,
    int N, int M)
{
    const int nt = B_ * N, ns = B_ * M;
    const int gid = blockIdx.x * 256 + threadIdx.x;
    const int stride = gridDim.x * 256;
    float s_t = 0.f, s_s = 0.f;
    for (int i = gid; i < nt; i += stride)
        s_t += sqrtf(__uint_as_float(minarr[i]));
    for (int i = gid; i < ns; i += stride)
        s_s += sqrtf(__uint_as_float(minarr[nt + i]));
#pragma unroll
    for (int off = 32; off > 0; off >>= 1) {
        s_t += __shfl_down(s_t, off);
        s_s += __shfl_down(s_s, off);
    }
    __shared__ float rt[4], rs[4];
    const int wid = threadIdx.x >> 6, lid = threadIdx.x & 63;
    if (lid == 0) { rt[wid] = s_t; rs[wid] = s_s; }
    __syncthreads();
    if (threadIdx.x == 0) {
        float ct = (rt[0] + rt[1] + rt[2] + rt[3]) / (float)nt;  // complete
        float ac = (rs[0] + rs[1] + rs[2] + rs[3]) / (float)ns;  // accuracy
        atomicAdd(&outp[0], ac);
        atomicAdd(&outp[1], ct);
        atomicAdd(&outp[2], 0.5f * (ac + ct));
    }
}

extern "C" void kernel_launch(void* const* d_in, const int* in_sizes, int n_in,
                              void* d_out, int out_size, void* d_ws, size_t ws_size,
                              hipStream_t stream) {
    const float* tar = (const float*)d_in[0];
    const float* src = (const float*)d_in[1];
    const int N = in_sizes[0] / (B_ * 3);
    const int M = in_sizes[1] / (B_ * 3);

    float4* packT = (float4*)d_ws;
    float4* packS = packT + (size_t)B_ * N;
    unsigned int* minarr = (unsigned int*)(packS + (size_t)B_ * M);
    float* outp = (float*)d_out;

    pack_kernel<<<dim3((B_ * (N + M) + 255) / 256), dim3(256), 0, stream>>>(
        tar, src, packT, packS, minarr, outp, N, M);

    constexpr int QPT = 8, CHUNK = 128;
    const int KL = (N > M) ? N : M;
    const int gx = (KL + 256 * QPT - 1) / (256 * QPT);   // 2
    const int gy = (KL + CHUNK - 1) / CHUNK;             // 32
    dim3 grid(gx, gy, 2 * B_);                            // 1024 blocks
    minsq_kernel<QPT, CHUNK><<<grid, dim3(256), 0, stream>>>(
        packT, packS, minarr, N, M);

    reduce_kernel<<<dim3(32), dim3(256), 0, stream>>>(minarr, outp, N, M);
}

// Round 3
// 86.496 us; speedup vs baseline: 1.1331x; 1.1331x over previous
//
#include <hip/hip_runtime.h>
#include <math.h>

#define B_ 8
#define BIGF 3.4e38f

typedef float f32x2 __attribute__((ext_vector_type(2)));
typedef float f32x4 __attribute__((ext_vector_type(4)));

// ws layout (16-B aligned base):
//   packT  : B_*N float4 {x,y,z,|t|^2}
//   packS  : B_*M float4 {x,y,z,|s|^2}
//   minarr : B_*N uint rowmin + B_*M uint colmin (uint-ordered float d^2)

__global__ __launch_bounds__(256) void pack_kernel(
    const float* __restrict__ tar, const float* __restrict__ src,
    float4* __restrict__ packT, float4* __restrict__ packS,
    unsigned int* __restrict__ minarr, float* __restrict__ outp,
    int N, int M)
{
    const int i = blockIdx.x * 256 + threadIdx.x;
    const int nT = B_ * N, nS = B_ * M;
    if (i < nT) {
        float x = tar[3 * i], y = tar[3 * i + 1], z = tar[3 * i + 2];
        packT[i] = make_float4(x, y, z, fmaf(x, x, fmaf(y, y, z * z)));
    } else if (i < nT + nS) {
        int j = i - nT;
        float x = src[3 * j], y = src[3 * j + 1], z = src[3 * j + 2];
        packS[j] = make_float4(x, y, z, fmaf(x, x, fmaf(y, y, z * z)));
    }
    if (i < nT + nS) minarr[i] = 0x7F800000u;  // +inf
    if (i < 3) outp[i] = 0.f;                  // accuracy, complete, chamfer
}

// R3: packed-FP32 inner loop. Post-mortems: R1 scalar-cache refetch = latency
// bound (93us); R2 readlane = VGPR-starved at 36 regs (41us, VALUBusy 72%).
// All variants sat at ~4 VALU-ops/pair; at the empirical ~0.65 issue
// efficiency (m07: scalar v_fma ubench = 103/157 TF) that's ~40us. Fix the
// INSTRUCTION COUNT: v_pk_fma_f32 (full-rate packed fp32 on CDNA) does 2
// FMAs/instr. Refs staged in LDS as SoA so one ds_read_b128 per coordinate
// delivers 4 refs = two packed f32x2 pairs. Query coeffs pre-splatted into
// f32x2 (no in-loop movs). Per 4 refs x query: 6 pk_fma + 2 min3 =
// 2.0 instr/pair. QPT=16 (gx=1) keeps DS demand below VALU: 8 waves/CU x
// 4 b128 x 12cy = 384 cy/CU-round vs 512 VALU cy/SIMD-round.
// __launch_bounds__(256,2) grants the ~180 VGPRs the working set needs.
// Ref tail padded with BIGF in LDS -> one uniform packed loop.
// Cross-block combine: distributed uint atomicMin (d^2 clamped >= 0).
template <int QPT, int CHUNK>
__global__ __launch_bounds__(256, 2) void minsq_kernel(
    const float4* __restrict__ packT, const float4* __restrict__ packS,
    unsigned int* __restrict__ minarr, int N, int M)
{
    const int z   = blockIdx.z;
    const int dir = (z >= B_) ? 1 : 0;
    const int b   = dir ? (z - B_) : z;
    const float4* __restrict__ qry = dir ? packS : packT;
    const float4* __restrict__ pts = dir ? packT : packS;
    const int K = dir ? M : N;   // query count
    const int L = dir ? N : M;   // reference count
    unsigned int* __restrict__ out =
        minarr + (dir ? (size_t)B_ * N : (size_t)0) + (size_t)b * K;

    const int base = blockIdx.y * CHUNK;
    if (base >= L) return;
    const int cnt = min(CHUNK, L - base);
    const float4* __restrict__ psrc = pts + (size_t)b * L + base;

    // SoA staging: x/y/z/w arrays so b128 reads give 4 refs per coordinate.
    __shared__ __align__(16) float sx[CHUNK], sy[CHUNK], sz[CHUNK], sw[CHUNK];
    const int t = threadIdx.x;
    for (int i = t; i < cnt; i += 256) {
        float4 p = psrc[i];
        sx[i] = p.x; sy[i] = p.y; sz[i] = p.z; sw[i] = p.w;
    }
    for (int i = cnt + t; i < CHUNK; i += 256) {       // BIGF-pad tail
        sx[i] = 0.f; sy[i] = 0.f; sz[i] = 0.f; sw[i] = BIGF;
    }
    __syncthreads();

    const int qbase = blockIdx.x * (256 * QPT);
    f32x2 qx[QPT], qy[QPT], qz[QPT];
    float qw[QPT], mn[QPT];
#pragma unroll
    for (int k = 0; k < QPT; ++k) {
        int qi = qbase + k * 256 + t;
        float ax = 0.f, ay = 0.f, az = 0.f, aw = 0.f;
        if (qi < K) {
            float4 q = qry[(size_t)b * K + qi];
            ax = -2.f * q.x; ay = -2.f * q.y; az = -2.f * q.z; aw = q.w;
        }
        qx[k].x = ax; qx[k].y = ax;
        qy[k].x = ay; qy[k].y = ay;
        qz[k].x = az; qz[k].y = az;
        qw[k] = aw;
        mn[k] = BIGF;
    }

    const f32x4* __restrict__ X4 = (const f32x4*)sx;
    const f32x4* __restrict__ Y4 = (const f32x4*)sy;
    const f32x4* __restrict__ Z4 = (const f32x4*)sz;
    const f32x4* __restrict__ W4 = (const f32x4*)sw;

#pragma unroll 2
    for (int j4 = 0; j4 < CHUNK / 4; ++j4) {
        f32x4 X = X4[j4], Y = Y4[j4], Z = Z4[j4], W = W4[j4];
        f32x2 x01; x01.x = X.x; x01.y = X.y;
        f32x2 x23; x23.x = X.z; x23.y = X.w;
        f32x2 y01; y01.x = Y.x; y01.y = Y.y;
        f32x2 y23; y23.x = Y.z; y23.y = Y.w;
        f32x2 z01; z01.x = Z.x; z01.y = Z.y;
        f32x2 z23; z23.x = Z.z; z23.y = Z.w;
        f32x2 w01; w01.x = W.x; w01.y = W.y;
        f32x2 w23; w23.x = W.z; w23.y = W.w;
#pragma unroll
        for (int k = 0; k < QPT; ++k) {
#if __has_builtin(__builtin_elementwise_fma)
            f32x2 dA = __builtin_elementwise_fma(qx[k], x01,
                       __builtin_elementwise_fma(qy[k], y01,
                       __builtin_elementwise_fma(qz[k], z01, w01)));
            f32x2 dB = __builtin_elementwise_fma(qx[k], x23,
                       __builtin_elementwise_fma(qy[k], y23,
                       __builtin_elementwise_fma(qz[k], z23, w23)));
#else
            f32x2 dA, dB;
            dA.x = fmaf(qx[k].x, x01.x, fmaf(qy[k].x, y01.x, fmaf(qz[k].x, z01.x, w01.x)));
            dA.y = fmaf(qx[k].y, x01.y, fmaf(qy[k].y, y01.y, fmaf(qz[k].y, z01.y, w01.y)));
            dB.x = fmaf(qx[k].x, x23.x, fmaf(qy[k].x, y23.x, fmaf(qz[k].x, z23.x, w23.x)));
            dB.y = fmaf(qx[k].y, x23.y, fmaf(qy[k].y, y23.y, fmaf(qz[k].y, z23.y, w23.y)));
#endif
            mn[k] = fminf(fminf(dA.x, dA.y), mn[k]);   // v_min3_f32
            mn[k] = fminf(fminf(dB.x, dB.y), mn[k]);   // v_min3_f32
        }
    }

#pragma unroll
    for (int k = 0; k < QPT; ++k) {
        int qi = qbase + k * 256 + t;
        if (qi < K) {
            float d2 = fmaxf(mn[k] + qw[k], 0.f);  // clamp roundoff negatives
            atomicMin(&out[qi], __float_as_uint(d2));
        }
    }
}

// Merged reduce+finalize: 32 blocks stripe-sum sqrt of both regions, then 3
// scaled atomicAdds into d_out (zeroed by pack_kernel).
__global__ __launch_bounds__(256) void reduce_kernel(
    const unsigned int* __restrict__ minarr, float* __restrict__ outp,
    int N, int M)
{
    const int nt = B_ * N, ns = B_ * M;
    const int gid = blockIdx.x * 256 + threadIdx.x;
    const int stride = gridDim.x * 256;
    float s_t = 0.f, s_s = 0.f;
    for (int i = gid; i < nt; i += stride)
        s_t += sqrtf(__uint_as_float(minarr[i]));
    for (int i = gid; i < ns; i += stride)
        s_s += sqrtf(__uint_as_float(minarr[nt + i]));
#pragma unroll
    for (int off = 32; off > 0; off >>= 1) {
        s_t += __shfl_down(s_t, off);
        s_s += __shfl_down(s_s, off);
    }
    __shared__ float rt[4], rs[4];
    const int wid = threadIdx.x >> 6, lid = threadIdx.x & 63;
    if (lid == 0) { rt[wid] = s_t; rs[wid] = s_s; }
    __syncthreads();
    if (threadIdx.x == 0) {
        float ct = (rt[0] + rt[1] + rt[2] + rt[3]) / (float)nt;  // complete
        float ac = (rs[0] + rs[1] + rs[2] + rs[3]) / (float)ns;  // accuracy
        atomicAdd(&outp[0], ac);
        atomicAdd(&outp[1], ct);
        atomicAdd(&outp[2], 0.5f * (ac + ct));
    }
}

extern "C" void kernel_launch(void* const* d_in, const int* in_sizes, int n_in,
                              void* d_out, int out_size, void* d_ws, size_t ws_size,
                              hipStream_t stream) {
    const float* tar = (const float*)d_in[0];
    const float* src = (const float*)d_in[1];
    const int N = in_sizes[0] / (B_ * 3);
    const int M = in_sizes[1] / (B_ * 3);

    float4* packT = (float4*)d_ws;
    float4* packS = packT + (size_t)B_ * N;
    unsigned int* minarr = (unsigned int*)(packS + (size_t)B_ * M);
    float* outp = (float*)d_out;

    pack_kernel<<<dim3((B_ * (N + M) + 255) / 256), dim3(256), 0, stream>>>(
        tar, src, packT, packS, minarr, outp, N, M);

    constexpr int QPT = 16, CHUNK = 128;
    const int KL = (N > M) ? N : M;
    const int gx = (KL + 256 * QPT - 1) / (256 * QPT);   // 1
    const int gy = (KL + CHUNK - 1) / CHUNK;             // 32
    dim3 grid(gx, gy, 2 * B_);                            // 512 blocks
    minsq_kernel<QPT, CHUNK><<<grid, dim3(256), 0, stream>>>(
        packT, packS, minarr, N, M);

    reduce_kernel<<<dim3(32), dim3(256), 0, stream>>>(minarr, outp, N, M);
}